// Round 17
// baseline (48.956 us; speedup 1.0000x reference)
//
#include <hip/hip_runtime.h>
#include <hip/hip_bf16.h>

// B=64, N=64, P=128, K=16, M=N*N=4096, T=4096
// Outputs: Z [64,64] then w [64,128,4096], concatenated f32.
//
// Pipeline (3 kernels):
//   K1 k_gemm  : blocks 0..1023   : part[tc][k][m] = sum_{256-t-chunk} W^2 G
//                XCD-swizzled (R16); 8 stages x 32 t (R17: halves the
//                vmcnt(0)-drain barrier count vs 16 x 16 t)
//                blocks 1024..1087: sbuf[b][k][j] = sum_{p:idx=k} x[b][p][j]
//                blocks 1088..1119: idxg[row] = argmax(xmask[row])
//   K2 k_reduce: wg = sum_tc part ; E = exp(-wg)
//   K3 k_wz    : blocks 0..2047   : w gather, 4 rows/block, idx precomputed
//                blocks 2048..2303: Z[b][i] = sum_k E[k][i,:].sbuf[b,k,:]
// Lessons: R5 no grid fences; R8 z-last; R10 cache policy neutral; R11/R12
// scatter loses to many-small-block gather; R14 gather thread-capped at 4
// rows/block; R15 riders under gemm free; R16 XCD swizzle +1.1us.

typedef float f32x4 __attribute__((ext_vector_type(4)));

__device__ __forceinline__ void dma16(const void* g, void* l) {
    __builtin_amdgcn_global_load_lds(
        (const __attribute__((address_space(1))) void*)g,
        (__attribute__((address_space(3))) void*)l, 16, 0, 0);
}

// ---------------------------------------------------------------------------
__global__ __launch_bounds__(256) void k_gemm(const float* __restrict__ W,
                                              const float* __restrict__ G,
                                              float* __restrict__ part,
                                              const float* __restrict__ x,
                                              const float* __restrict__ xmask,
                                              float* __restrict__ sbuf,
                                              int* __restrict__ idxg) {
    __shared__ float buf[12288];              // 48 KB... no: see carve below
    const int tid = threadIdx.x;
    const int wv  = tid >> 6;
    const int ln  = tid & 63;

    if (blockIdx.x >= 1088) {
        // ---- idx decode riders: 1 row per thread, fully parallel ----
        const int row = (blockIdx.x - 1088) * 256 + tid;   // 0..8191
        const float* xm = xmask + (size_t)row * 16;
        int k = 0;
#pragma unroll
        for (int j = 0; j < 16; ++j) k = (xm[j] > 0.5f) ? j : k;
        idxg[row] = k;
        return;
    }

    if (blockIdx.x >= 1024) {
        // ---- s-accumulation for batch b (verified R7 code) ----
        const int b = blockIdx.x - 1024;
        float* sw  = buf;                     // [4][16][64] = 16 KB
        int*  idxp = (int*)(buf + 4096);      // 128 ints
        if (tid < 128) {
            const float* xm = xmask + ((size_t)b * 128 + tid) * 16;
            int k = 0;
#pragma unroll
            for (int i = 0; i < 16; ++i) k = (xm[i] > 0.5f) ? i : k;
            idxp[tid] = k;
        }
#pragma unroll
        for (int c = 0; c < 16; ++c) sw[c * 256 + tid] = 0.f;
        __syncthreads();
        const float* xb = x + (size_t)b * 8192;
        for (int p = wv * 32; p < wv * 32 + 32; ++p)
            sw[wv * 1024 + idxp[p] * 64 + ln] += xb[p * 64 + ln];
        __syncthreads();
        for (int e = tid; e < 1024; e += 256)
            sbuf[b * 1024 + e] = sw[e] + sw[1024 + e] + sw[2048 + e] + sw[3072 + e];
        return;
    }

    // ---- GEMM path ----
    // LDS carve: w2t [256][4]f4 = 16 KB at buf[0..4095];
    //            stage 2 x 512 f4 = 16 KB at buf[4096..12287].
    float4* w2t4 = (float4*)buf;
    float4* stg  = (float4*)(buf + 4096);

    // XCD-aware swizzle (R16): XCD x owns tc {2x, 2x+1}.
    const int xcd = blockIdx.x & 7;
    const int j   = blockIdx.x >> 3;          // 0..127
    const int tc  = 2 * xcd + (j >> 6);       // t-chunk (256 t each)
    const int mg  = j & 63;                   // m-slice (64 floats)
    const int tt  = tid >> 4;                 // 0..15 t-sublane
    const int t0  = tc * 256;

    {
        float v[16];
#pragma unroll
        for (int k = 0; k < 16; ++k) {
            float w = W[k * 4096 + t0 + tid];
            v[k] = w * w;
        }
#pragma unroll
        for (int q = 0; q < 4; ++q) {
            const int slot = (q + (tid >> 1)) & 3;
            w2t4[tid * 4 + slot] =
                make_float4(v[4*q], v[4*q+1], v[4*q+2], v[4*q+3]);
        }
    }

    const float4* G4 = (const float4*)G;
    const int fi  = wv * 64 + ln;
    const int tl_ = fi >> 4;                  // row within a 16-t half-tile
    const int mc_ = fi & 15;                  // f4-col
    const size_t gbase = (size_t)mg * 16 + mc_;

    // stage 0: t = t0..t0+31 via two 16-t DMA halves
    dma16(&G4[(size_t)(t0 + tl_) * 1024 + gbase],      &stg[wv * 64]);
    dma16(&G4[(size_t)(t0 + 16 + tl_) * 1024 + gbase], &stg[256 + wv * 64]);
    __syncthreads();                          // drains w2t writes + stage-0 DMA

    float4 acc[16];
#pragma unroll
    for (int k = 0; k < 16; ++k) acc[k] = make_float4(0.f, 0.f, 0.f, 0.f);

    for (int s = 0; s < 8; ++s) {             // 8 stages x 32 t (R17)
        if (s < 7) {
            const int tn = t0 + (s + 1) * 32;
            const int db = ((s + 1) & 1) * 512;
            dma16(&G4[(size_t)(tn + tl_) * 1024 + gbase],      &stg[db + wv * 64]);
            dma16(&G4[(size_t)(tn + 16 + tl_) * 1024 + gbase], &stg[db + 256 + wv * 64]);
        }
        const int db = (s & 1) * 512;
        const float4 g4a = stg[db + tid];         // t = s*32 + tt
        const float4 g4b = stg[db + 256 + tid];   // t = s*32 + 16 + tt
        const int ra = s * 32 + tt;
        const int rb = ra + 16;
#pragma unroll
        for (int q = 0; q < 4; ++q) {
            const int sa = (q + (ra >> 1)) & 3;   // un-rotate
            const int sb = (q + (rb >> 1)) & 3;
            const float4 wqa = w2t4[ra * 4 + sa];
            const float4 wqb = w2t4[rb * 4 + sb];
            const float* wfa = (const float*)&wqa;
            const float* wfb = (const float*)&wqb;
#pragma unroll
            for (int c = 0; c < 4; ++c) {
                const float fa = wfa[c];
                const float fb = wfb[c];
                acc[q*4+c].x = fmaf(fa, g4a.x, fmaf(fb, g4b.x, acc[q*4+c].x));
                acc[q*4+c].y = fmaf(fa, g4a.y, fmaf(fb, g4b.y, acc[q*4+c].y));
                acc[q*4+c].z = fmaf(fa, g4a.z, fmaf(fb, g4b.z, acc[q*4+c].z));
                acc[q*4+c].w = fmaf(fa, g4a.w, fmaf(fb, g4b.w, acc[q*4+c].w));
            }
        }
        __syncthreads();   // drain: next tile landed; buffer reuse safe
    }

    // in-block reduction over tt: 2 rounds of 8 k (red aliases buf)
    float4* red = (float4*)buf;
    float4* p4  = (float4*)part;
#pragma unroll
    for (int r = 0; r < 2; ++r) {
#pragma unroll
        for (int ks = 0; ks < 8; ++ks)
            red[ks * 256 + tid] = acc[r * 8 + ks];
        __syncthreads();
        if (tid < 128) {
            const int ks = tid >> 4;
            const int c2 = tid & 15;
            float4 s = make_float4(0.f, 0.f, 0.f, 0.f);
#pragma unroll
            for (int t2 = 0; t2 < 16; ++t2) {
                float4 v = red[ks * 256 + t2 * 16 + c2];
                s.x += v.x; s.y += v.y; s.z += v.z; s.w += v.w;
            }
            const int k = r * 8 + ks;
            p4[(size_t)tc * 16384 + (size_t)k * 1024 + mg * 16 + c2] = s;
        }
        __syncthreads();
    }
}

// ---------------------------------------------------------------------------
// grid 256 x 64: thread owns one float4 of wg/E, sums 16 tc partials.
__global__ __launch_bounds__(64) void k_reduce(const float* __restrict__ part,
                                               float* __restrict__ wg,
                                               float* __restrict__ E) {
    const int q = blockIdx.x * 64 + threadIdx.x;     // f4 id 0..16383
    const float4* p4 = (const float4*)part;
    float4 s = make_float4(0.f, 0.f, 0.f, 0.f);
#pragma unroll
    for (int tc = 0; tc < 16; ++tc) {
        float4 v = p4[(size_t)tc * 16384 + q];
        s.x += v.x; s.y += v.y; s.z += v.z; s.w += v.w;
    }
    ((float4*)wg)[q] = s;
    ((float4*)E)[q] = make_float4(expf(-s.x), expf(-s.y), expf(-s.z), expf(-s.w));
}

// ---------------------------------------------------------------------------
// blocks 0..2047: w gather, 4 rows/block, precomputed idx, no LDS/sync.
// blocks 2048..2303: Z (b = zb>>2, iq = zb&3) from sbuf.
__global__ __launch_bounds__(256) void k_wz(const int* __restrict__ idxg,
                                            const float* __restrict__ wg,
                                            const float* __restrict__ E,
                                            const float* __restrict__ sbuf,
                                            float* __restrict__ wout,
                                            float* __restrict__ zout) {
    __shared__ float zr[16][16];      // 1 KB (z path only)
    const int tid = threadIdx.x;

    if (blockIdx.x < 2048) {
        const int bp0 = blockIdx.x * 4;
        const int k0 = idxg[bp0 + 0];
        const int k1 = idxg[bp0 + 1];
        const int k2 = idxg[bp0 + 2];
        const int k3 = idxg[bp0 + 3];
        const f32x4* s0 = (const f32x4*)(wg + (size_t)k0 * 4096);
        const f32x4* s1 = (const f32x4*)(wg + (size_t)k1 * 4096);
        const f32x4* s2 = (const f32x4*)(wg + (size_t)k2 * 4096);
        const f32x4* s3 = (const f32x4*)(wg + (size_t)k3 * 4096);
        f32x4* d = (f32x4*)(wout + (size_t)bp0 * 4096);
#pragma unroll
        for (int c = 0; c < 4; ++c) {
            const int o = c * 256 + tid;
            d[o]        = s0[o];
            d[1024 + o] = s1[o];
            d[2048 + o] = s2[o];
            d[3072 + o] = s3[o];
        }
        return;
    }

    // ---- Z path ----
    const int zb = blockIdx.x - 2048;
    const int b  = zb >> 2;
    const int iq = zb & 3;
    {
        const int k  = tid >> 4;
        const int il = tid & 15;
        const int i  = iq * 16 + il;
        float a = 0.f;
        const float4* Er = (const float4*)(E + (size_t)k * 4096 + i * 64);
        const float4* sr = (const float4*)(sbuf + (size_t)b * 1024 + k * 64);
#pragma unroll
        for (int j4 = 0; j4 < 16; ++j4) {
            float4 e4 = Er[j4];
            float4 s4 = sr[j4];
            a = fmaf(e4.x, s4.x, a);
            a = fmaf(e4.y, s4.y, a);
            a = fmaf(e4.z, s4.z, a);
            a = fmaf(e4.w, s4.w, a);
        }
        zr[k][il] = a;
    }
    __syncthreads();
    if (tid < 16) {
        float s = 0.f;
#pragma unroll
        for (int kk = 0; kk < 16; ++kk) s += zr[kk][tid];
        zout[b * 64 + iq * 16 + tid] = s;
    }
}

extern "C" void kernel_launch(void* const* d_in, const int* in_sizes, int n_in,
                              void* d_out, int out_size, void* d_ws, size_t ws_size,
                              hipStream_t stream) {
    const float* x     = (const float*)d_in[0];   // [64,64,128]
    const float* xmask = (const float*)d_in[1];   // [64,128,16]
    const float* W     = (const float*)d_in[2];   // [16,4096]
    const float* G     = (const float*)d_in[3];   // [4096,4096]

    float* zout = (float*)d_out;                  // [64,64]
    float* wout = (float*)d_out + 4096;           // [64,128,4096]

    float* wg   = (float*)d_ws;                   // 64K f32 (256 KB)
    float* E    = wg + 65536;                     // 64K f32 (256 KB)
    float* sbuf = E + 65536;                      // 64K f32 (256 KB)
    int*   idxg = (int*)(sbuf + 65536);           // 8192 ints (32 KB)

    // partials live in the (dead-until-overwritten) w output region: 4 MB
    float* part = wout;

    k_gemm  <<<1120, 256, 0, stream>>>(W, G, part, x, xmask, sbuf, idxg);
    k_reduce<<<256,  64,  0, stream>>>(part, wg, E);
    k_wz    <<<2304, 256, 0, stream>>>(idxg, wg, E, sbuf, wout, zout);
}

// Round 18
// 46.116 us; speedup vs baseline: 1.0616x; 1.0616x over previous
//
#include <hip/hip_runtime.h>
#include <hip/hip_bf16.h>

// B=64, N=64, P=128, K=16, M=N*N=4096, T=4096
// Outputs: Z [64,64] then w [64,128,4096], concatenated f32.
//
// Pipeline (3 kernels) — FINAL (R16 config, best measured 46.1 us):
//   K1 k_gemm  : blocks 0..1023   : part[tc][k][m] = sum_{256-t-chunk} W^2 G
//                XCD-swizzled (R16); 16 stages x 16 t (R17 lesson: 32-t
//                stages regress ~3us — 16-stage pipeline is the optimum)
//                blocks 1024..1087: sbuf[b][k][j] = sum_{p:idx=k} x[b][p][j]
//                blocks 1088..1119: idxg[row] = argmax(xmask[row])
//   K2 k_reduce: wg = sum_tc part ; E = exp(-wg)
//   K3 k_wz    : blocks 0..2047   : w gather, 4 rows/block, idx precomputed
//                blocks 2048..2303: Z[b][i] = sum_k E[k][i,:].sbuf[b,k,:]
// Lessons: R5 no grid fences; R8 z-last; R10 cache policy neutral; R11/R12
// scatter loses to many-small-block gather; R14 gather thread-capped at 4
// rows/block; R15 riders under gemm free; R16 XCD swizzle +1.1us; R17 wide
// stages regress.

typedef float f32x4 __attribute__((ext_vector_type(4)));

__device__ __forceinline__ void dma16(const void* g, void* l) {
    __builtin_amdgcn_global_load_lds(
        (const __attribute__((address_space(1))) void*)g,
        (__attribute__((address_space(3))) void*)l, 16, 0, 0);
}

// ---------------------------------------------------------------------------
__global__ __launch_bounds__(256) void k_gemm(const float* __restrict__ W,
                                              const float* __restrict__ G,
                                              float* __restrict__ part,
                                              const float* __restrict__ x,
                                              const float* __restrict__ xmask,
                                              float* __restrict__ sbuf,
                                              int* __restrict__ idxg) {
    __shared__ float buf[8192];               // 32 KB
    const int tid = threadIdx.x;
    const int wv  = tid >> 6;
    const int ln  = tid & 63;

    if (blockIdx.x >= 1088) {
        // ---- idx decode riders: 1 row per thread, fully parallel ----
        const int row = (blockIdx.x - 1088) * 256 + tid;   // 0..8191
        const float* xm = xmask + (size_t)row * 16;
        int k = 0;
#pragma unroll
        for (int j = 0; j < 16; ++j) k = (xm[j] > 0.5f) ? j : k;
        idxg[row] = k;
        return;
    }

    if (blockIdx.x >= 1024) {
        // ---- s-accumulation for batch b (verified R7 code) ----
        const int b = blockIdx.x - 1024;
        float* sw  = buf;                     // [4][16][64] = 16 KB
        int*  idxp = (int*)(buf + 4096);      // 128 ints
        if (tid < 128) {
            const float* xm = xmask + ((size_t)b * 128 + tid) * 16;
            int k = 0;
#pragma unroll
            for (int i = 0; i < 16; ++i) k = (xm[i] > 0.5f) ? i : k;
            idxp[tid] = k;
        }
#pragma unroll
        for (int c = 0; c < 16; ++c) sw[c * 256 + tid] = 0.f;
        __syncthreads();
        const float* xb = x + (size_t)b * 8192;
        for (int p = wv * 32; p < wv * 32 + 32; ++p)
            sw[wv * 1024 + idxp[p] * 64 + ln] += xb[p * 64 + ln];
        __syncthreads();
        for (int e = tid; e < 1024; e += 256)
            sbuf[b * 1024 + e] = sw[e] + sw[1024 + e] + sw[2048 + e] + sw[3072 + e];
        return;
    }

    // ---- GEMM path ----
    float4* w2t4 = (float4*)buf;              // w2t[256][4 quads] = 16 KB
    float4* stg  = (float4*)(buf + 4096);     // 2 stage buffers x 256 f4 = 8 KB

    // XCD-aware swizzle (R16): XCD x owns tc {2x, 2x+1} -> its 128 blocks
    // share an 8 MB G window inside one L2 instead of streaming all 64 MB.
    const int xcd = blockIdx.x & 7;
    const int j   = blockIdx.x >> 3;          // 0..127
    const int tc  = 2 * xcd + (j >> 6);       // t-chunk (256 t each)
    const int mg  = j & 63;                   // m-slice (64 floats)
    const int tt  = tid >> 4;                 // 0..15 t-sublane
    const int t0  = tc * 256;

    {
        float v[16];
#pragma unroll
        for (int k = 0; k < 16; ++k) {
            float w = W[k * 4096 + t0 + tid];
            v[k] = w * w;
        }
#pragma unroll
        for (int q = 0; q < 4; ++q) {
            const int slot = (q + (tid >> 1)) & 3;
            w2t4[tid * 4 + slot] =
                make_float4(v[4*q], v[4*q+1], v[4*q+2], v[4*q+3]);
        }
    }

    const float4* G4 = (const float4*)G;
    const int fi  = wv * 64 + ln;
    const int tl_ = fi >> 4;
    const int mc_ = fi & 15;

    dma16(&G4[(size_t)(t0 + tl_) * 1024 + mg * 16 + mc_], &stg[wv * 64]);
    __syncthreads();

    float4 acc[16];
#pragma unroll
    for (int k = 0; k < 16; ++k) acc[k] = make_float4(0.f, 0.f, 0.f, 0.f);

    for (int s = 0; s < 16; ++s) {
        if (s < 15)
            dma16(&G4[(size_t)(t0 + (s + 1) * 16 + tl_) * 1024 + mg * 16 + mc_],
                  &stg[((s + 1) & 1) * 256 + wv * 64]);

        const float4 g4 = stg[(s & 1) * 256 + tid];
        const int r = s * 16 + tt;
#pragma unroll
        for (int q = 0; q < 4; ++q) {
            const int slot = (q + (r >> 1)) & 3;
            const float4 wq = w2t4[r * 4 + slot];
            const float* wf = (const float*)&wq;
#pragma unroll
            for (int c = 0; c < 4; ++c) {
                const float sc = wf[c];
                acc[q*4+c].x = fmaf(sc, g4.x, acc[q*4+c].x);
                acc[q*4+c].y = fmaf(sc, g4.y, acc[q*4+c].y);
                acc[q*4+c].z = fmaf(sc, g4.z, acc[q*4+c].z);
                acc[q*4+c].w = fmaf(sc, g4.w, acc[q*4+c].w);
            }
        }
        __syncthreads();
    }

    float4* red = (float4*)buf;
    float4* p4  = (float4*)part;
#pragma unroll
    for (int r = 0; r < 2; ++r) {
#pragma unroll
        for (int ks = 0; ks < 8; ++ks)
            red[ks * 256 + tid] = acc[r * 8 + ks];
        __syncthreads();
        if (tid < 128) {
            const int ks = tid >> 4;
            const int c2 = tid & 15;
            float4 s = make_float4(0.f, 0.f, 0.f, 0.f);
#pragma unroll
            for (int t2 = 0; t2 < 16; ++t2) {
                float4 v = red[ks * 256 + t2 * 16 + c2];
                s.x += v.x; s.y += v.y; s.z += v.z; s.w += v.w;
            }
            const int k = r * 8 + ks;
            p4[(size_t)tc * 16384 + (size_t)k * 1024 + mg * 16 + c2] = s;
        }
        __syncthreads();
    }
}

// ---------------------------------------------------------------------------
// grid 256 x 64: thread owns one float4 of wg/E, sums 16 tc partials.
__global__ __launch_bounds__(64) void k_reduce(const float* __restrict__ part,
                                               float* __restrict__ wg,
                                               float* __restrict__ E) {
    const int q = blockIdx.x * 64 + threadIdx.x;     // f4 id 0..16383
    const float4* p4 = (const float4*)part;
    float4 s = make_float4(0.f, 0.f, 0.f, 0.f);
#pragma unroll
    for (int tc = 0; tc < 16; ++tc) {
        float4 v = p4[(size_t)tc * 16384 + q];
        s.x += v.x; s.y += v.y; s.z += v.z; s.w += v.w;
    }
    ((float4*)wg)[q] = s;
    ((float4*)E)[q] = make_float4(expf(-s.x), expf(-s.y), expf(-s.z), expf(-s.w));
}

// ---------------------------------------------------------------------------
// blocks 0..2047: w gather, 4 rows/block, precomputed idx, no LDS/sync.
// blocks 2048..2303: Z (b = zb>>2, iq = zb&3) from sbuf.
__global__ __launch_bounds__(256) void k_wz(const int* __restrict__ idxg,
                                            const float* __restrict__ wg,
                                            const float* __restrict__ E,
                                            const float* __restrict__ sbuf,
                                            float* __restrict__ wout,
                                            float* __restrict__ zout) {
    __shared__ float zr[16][16];      // 1 KB (z path only)
    const int tid = threadIdx.x;

    if (blockIdx.x < 2048) {
        const int bp0 = blockIdx.x * 4;
        const int k0 = idxg[bp0 + 0];
        const int k1 = idxg[bp0 + 1];
        const int k2 = idxg[bp0 + 2];
        const int k3 = idxg[bp0 + 3];
        const f32x4* s0 = (const f32x4*)(wg + (size_t)k0 * 4096);
        const f32x4* s1 = (const f32x4*)(wg + (size_t)k1 * 4096);
        const f32x4* s2 = (const f32x4*)(wg + (size_t)k2 * 4096);
        const f32x4* s3 = (const f32x4*)(wg + (size_t)k3 * 4096);
        f32x4* d = (f32x4*)(wout + (size_t)bp0 * 4096);
#pragma unroll
        for (int c = 0; c < 4; ++c) {
            const int o = c * 256 + tid;
            d[o]        = s0[o];
            d[1024 + o] = s1[o];
            d[2048 + o] = s2[o];
            d[3072 + o] = s3[o];
        }
        return;
    }

    // ---- Z path ----
    const int zb = blockIdx.x - 2048;
    const int b  = zb >> 2;
    const int iq = zb & 3;
    {
        const int k  = tid >> 4;
        const int il = tid & 15;
        const int i  = iq * 16 + il;
        float a = 0.f;
        const float4* Er = (const float4*)(E + (size_t)k * 4096 + i * 64);
        const float4* sr = (const float4*)(sbuf + (size_t)b * 1024 + k * 64);
#pragma unroll
        for (int j4 = 0; j4 < 16; ++j4) {
            float4 e4 = Er[j4];
            float4 s4 = sr[j4];
            a = fmaf(e4.x, s4.x, a);
            a = fmaf(e4.y, s4.y, a);
            a = fmaf(e4.z, s4.z, a);
            a = fmaf(e4.w, s4.w, a);
        }
        zr[k][il] = a;
    }
    __syncthreads();
    if (tid < 16) {
        float s = 0.f;
#pragma unroll
        for (int kk = 0; kk < 16; ++kk) s += zr[kk][tid];
        zout[b * 64 + iq * 16 + tid] = s;
    }
}

extern "C" void kernel_launch(void* const* d_in, const int* in_sizes, int n_in,
                              void* d_out, int out_size, void* d_ws, size_t ws_size,
                              hipStream_t stream) {
    const float* x     = (const float*)d_in[0];   // [64,64,128]
    const float* xmask = (const float*)d_in[1];   // [64,128,16]
    const float* W     = (const float*)d_in[2];   // [16,4096]
    const float* G     = (const float*)d_in[3];   // [4096,4096]

    float* zout = (float*)d_out;                  // [64,64]
    float* wout = (float*)d_out + 4096;           // [64,128,4096]

    float* wg   = (float*)d_ws;                   // 64K f32 (256 KB)
    float* E    = wg + 65536;                     // 64K f32 (256 KB)
    float* sbuf = E + 65536;                      // 64K f32 (256 KB)
    int*   idxg = (int*)(sbuf + 65536);           // 8192 ints (32 KB)

    // partials live in the (dead-until-overwritten) w output region: 4 MB
    float* part = wout;

    k_gemm  <<<1120, 256, 0, stream>>>(W, G, part, x, xmask, sbuf, idxg);
    k_reduce<<<256,  64,  0, stream>>>(part, wg, E);
    k_wz    <<<2304, 256, 0, stream>>>(idxg, wg, E, sbuf, wout, zout);
}